// Round 1
// baseline (1090.657 us; speedup 1.0000x reference)
//
#include <hip/hip_runtime.h>
#include <math.h>

#define B_    16
#define L_    512
#define V_    32
#define D_    128
#define DFF_  256
#define PL_   16
#define ST_   8
#define PRED_ 96
#define DI_   256
#define DS_   16
#define DTR_  8
#define H_    8
#define HD_   32
#define KC_   4
#define P_    64
#define NF_   8192
#define BV_   (B_*V_)    // 512
#define NP_   (BV_*P_)   // 32768

__device__ __forceinline__ float siluf(float x){ return x / (1.f + expf(-x)); }
__device__ __forceinline__ float geluf(float x){
    const float c = 0.7978845608028654f;
    float t = tanhf(c*(x + 0.044715f*x*x*x));
    return 0.5f*x*(1.f+t);
}
__device__ __forceinline__ float softplusf(float x){ return (x > 20.f) ? x : log1pf(expf(x)); }

// ---------------------------------------------------------------- stats + normalize + transpose
__global__ void stats_kernel(const float* __restrict__ x_enc, float* __restrict__ meanb,
                             float* __restrict__ stdevb, float* __restrict__ xc)
{
    int bv = blockIdx.x; int b = bv >> 5; int v = bv & 31;
    int tid = threadIdx.x; // 256
    float x0 = x_enc[((long)b*L_ + tid)*V_ + v];
    float x1 = x_enc[((long)b*L_ + tid + 256)*V_ + v];
    __shared__ float rs[256], rq[256];
    rs[tid] = x0 + x1; rq[tid] = x0*x0 + x1*x1;
    __syncthreads();
    for (int s = 128; s > 0; s >>= 1){
        if (tid < s){ rs[tid] += rs[tid+s]; rq[tid] += rq[tid+s]; }
        __syncthreads();
    }
    __shared__ float smean, sinv;
    if (tid == 0){
        float m = rs[0] / (float)L_;
        float var = rq[0] / (float)L_ - m*m;
        float sd = sqrtf(var + 1e-5f);
        meanb[bv] = m; stdevb[bv] = sd;
        smean = m; sinv = 1.f/sd;
    }
    __syncthreads();
    xc[(long)bv*L_ + tid]       = (x0 - smean)*sinv;
    xc[(long)bv*L_ + tid + 256] = (x1 - smean)*sinv;
}

// ---------------------------------------------------------------- patch embedding
__global__ void patch_kernel(const float* __restrict__ xc, const float* __restrict__ Wp,
                             const float* __restrict__ bp, float* __restrict__ tw)
{
    int bv = blockIdx.x;
    __shared__ float sx[L_ + ST_];       // 520
    __shared__ float sw[D_ * PL_];       // 2048
    for (int i = threadIdx.x; i < L_ + ST_; i += 256) sx[i] = xc[(long)bv*L_ + (i < L_ ? i : L_-1)];
    for (int i = threadIdx.x; i < D_*PL_; i += 256) sw[i] = Wp[i];
    __syncthreads();
    for (int o = threadIdx.x; o < P_*D_; o += 256){
        int p = o >> 7; int dd = o & 127;
        float acc = bp[dd];
        #pragma unroll
        for (int k = 0; k < PL_; k++) acc += sx[p*ST_ + k] * sw[dd*PL_ + k];
        tw[((long)bv*P_ + p)*D_ + dd] = acc;
    }
}

// ---------------------------------------------------------------- channel embedding (cw = xc @ W_chan.T + b)
__global__ void chan_kernel(const float* __restrict__ xc, const float* __restrict__ Wc,
                            const float* __restrict__ bc, float* __restrict__ cw)
{
    int bv = blockIdx.x; int tid = threadIdx.x; // 128
    __shared__ float sx[L_];
    for (int i = tid; i < L_; i += 128) sx[i] = xc[(long)bv*L_ + i];
    __syncthreads();
    const float* wp = Wc + (long)tid*L_;
    float acc = bc[tid];
    for (int k = 0; k < L_; k += 4){
        float4 w4 = *(const float4*)(wp + k);
        acc += sx[k]*w4.x + sx[k+1]*w4.y + sx[k+2]*w4.z + sx[k+3]*w4.w;
    }
    cw[(long)bv*D_ + tid] = acc;
}

// ---------------------------------------------------------------- generic fp32 GEMM: C = act(A@W^T + bias) (+ residual)
// A: (M, lda), uses cols 0..K-1.  W: (N, K) row-major.  act: 0 none, 1 gelu.
#define BM 64
#define BN 64
#define BK 16
__global__ void gemm_kernel(const float* __restrict__ A, int lda,
                            const float* __restrict__ W,
                            const float* __restrict__ bias,
                            const float* __restrict__ residual, int ldr,
                            float* __restrict__ C, int ldc,
                            int M, int N, int K, int act)
{
    __shared__ float As[BK][BM+1];
    __shared__ float Ws[BK][BN+1];
    int tid = threadIdx.x;
    int block_row = blockIdx.x * BM;
    int block_col = blockIdx.y * BN;
    int tr = (tid >> 4) * 4;
    int tc = (tid & 15) * 4;
    float acc[4][4] = {};
    for (int k0 = 0; k0 < K; k0 += BK){
        for (int i = tid; i < BM*BK; i += 256){
            int r = i >> 4, c = i & 15;
            int gr = block_row + r, gc = k0 + c;
            As[c][r] = (gr < M && gc < K) ? A[(long)gr*lda + gc] : 0.f;
        }
        for (int i = tid; i < BN*BK; i += 256){
            int r = i >> 4, c = i & 15;
            int gr = block_col + r, gc = k0 + c;
            Ws[c][r] = (gr < N && gc < K) ? W[(long)gr*K + gc] : 0.f;
        }
        __syncthreads();
        #pragma unroll
        for (int k = 0; k < BK; k++){
            float a[4], w[4];
            #pragma unroll
            for (int i = 0; i < 4; i++) a[i] = As[k][tr+i];
            #pragma unroll
            for (int j = 0; j < 4; j++) w[j] = Ws[k][tc+j];
            #pragma unroll
            for (int i = 0; i < 4; i++)
                #pragma unroll
                for (int j = 0; j < 4; j++)
                    acc[i][j] += a[i]*w[j];
        }
        __syncthreads();
    }
    for (int i = 0; i < 4; i++){
        int gr = block_row + tr + i;
        if (gr >= M) continue;
        for (int j = 0; j < 4; j++){
            int gc = block_col + tc + j;
            if (gc >= N) continue;
            float v = acc[i][j];
            if (bias) v += bias[gc];
            if (act == 1) v = geluf(v);
            if (residual) v += residual[(long)gr*ldr + gc];
            C[(long)gr*ldc + gc] = v;
        }
    }
}

// ---------------------------------------------------------------- mamba depthwise causal conv + silu (in place on xm cols of xmz)
__global__ void mamba_conv_kernel(float* __restrict__ xmz, const float* __restrict__ w,
                                  const float* __restrict__ b)
{
    int n = blockIdx.x; int d = threadIdx.x; // 256
    float w0 = w[d*4+0], w1 = w[d*4+1], w2 = w[d*4+2], w3 = w[d*4+3];
    float bb = b[d];
    float x1 = 0.f, x2 = 0.f, x3 = 0.f;
    for (int t = 0; t < P_; t++){
        long idx = ((long)n*P_ + t)*(2*DI_) + d;
        float x0 = xmz[idx];
        float y = w3*x0 + w2*x1 + w1*x2 + w0*x3 + bb;
        xmz[idx] = siluf(y);
        x3 = x2; x2 = x1; x1 = x0;
    }
}

// ---------------------------------------------------------------- mamba selective scan (fused dt-proj + softplus + gating)
// xmz: (NP, 512)  cols 0..255 = xm (silu'd), cols 256..511 = z.  Writes gated y into cols 0..255.
__global__ void mamba_scan_kernel(float* __restrict__ xmz, const float* __restrict__ dtbc,
                                  const float* __restrict__ Wdt, const float* __restrict__ bdt,
                                  const float* __restrict__ Alog, const float* __restrict__ Dvec)
{
    int n = blockIdx.x; int d = threadIdx.x; // 256
    float A[DS_];
    #pragma unroll
    for (int s = 0; s < DS_; s++) A[s] = -expf(Alog[d*DS_ + s]);
    float wdt[DTR_];
    #pragma unroll
    for (int j = 0; j < DTR_; j++) wdt[j] = Wdt[d*DTR_ + j];
    float bd = bdt[d];
    float Dd = Dvec[d];
    float h[DS_] = {};
    __shared__ float sRow[40]; // dt8 | B16 | C16
    for (int t = 0; t < P_; t++){
        long row = (long)n*P_ + t;
        if (d < 40) sRow[d] = dtbc[row*40 + d];
        __syncthreads();
        float dtr = bd;
        #pragma unroll
        for (int j = 0; j < DTR_; j++) dtr += sRow[j]*wdt[j];
        float dt = softplusf(dtr);
        float x = xmz[row*(2*DI_) + d];
        float dtx = dt*x;
        float y = 0.f;
        #pragma unroll
        for (int s = 0; s < DS_; s++){
            h[s] = expf(dt*A[s])*h[s] + dtx*sRow[DTR_ + s];
            y += h[s]*sRow[DTR_ + DS_ + s];
        }
        y += Dd*x;
        float z = xmz[row*(2*DI_) + DI_ + d];
        xmz[row*(2*DI_) + d] = y * siluf(z);
        __syncthreads();
    }
}

// ---------------------------------------------------------------- hy depthwise conv + silu (zx cols 256..543 -> xbc)
__global__ void hy_conv_kernel(const float* __restrict__ zx, float* __restrict__ xbc,
                               const float* __restrict__ w, const float* __restrict__ b)
{
    int bb = blockIdx.x; int c = threadIdx.x; // 320 threads
    if (c >= 288) return;
    float w0 = w[c*4+0], w1 = w[c*4+1], w2 = w[c*4+2], w3 = w[c*4+3];
    float bias = b[c];
    float x1 = 0.f, x2 = 0.f, x3 = 0.f;
    for (int v = 0; v < V_; v++){
        float x0 = zx[((long)(bb*V_+v))*552 + 256 + c];
        float y = w3*x0 + w2*x1 + w1*x2 + w0*x3 + bias;
        xbc[((long)(bb*V_+v))*288 + c] = siluf(y);
        x3 = x2; x2 = x1; x1 = x0;
    }
}

// ---------------------------------------------------------------- dth = softplus(zx[...,544:552] + hy_bdt)
__global__ void dth_kernel(const float* __restrict__ zx, const float* __restrict__ bdt,
                           float* __restrict__ dth)
{
    int idx = blockIdx.x*256 + threadIdx.x;
    if (idx >= BV_*H_) return;
    int row = idx >> 3; int hh = idx & 7;
    dth[idx] = softplusf(zx[(long)row*552 + 544 + hh] + bdt[hh]);
}

// ---------------------------------------------------------------- bidirectional SSD scan
__global__ void ssd_kernel(const float* __restrict__ xbc, const float* __restrict__ dth,
                           float* __restrict__ yh, const float* __restrict__ Alog,
                           const float* __restrict__ Dvec)
{
    int b = blockIdx.x; int tid = threadIdx.x; // 256
    int hh = tid >> 5; int d = tid & 31;
    float Ah = -expf(Alog[hh]);
    float Dh = Dvec[hh];
    __shared__ float sdt[H_], sB[DS_], sC[DS_];
    float st[DS_] = {};
    // forward
    for (int v = 0; v < V_; v++){
        long row = (long)b*V_ + v;
        if (tid < H_) sdt[tid] = dth[row*H_ + tid];
        else if (tid < H_+DS_) sB[tid-H_] = xbc[row*288 + 256 + (tid-H_)];
        else if (tid < H_+2*DS_) sC[tid-H_-DS_] = xbc[row*288 + 272 + (tid-H_-DS_)];
        __syncthreads();
        float dt = sdt[hh];
        float x = xbc[row*288 + tid];
        float decay = expf(dt*Ah);
        float dtx = dt*x;
        float y = 0.f;
        #pragma unroll
        for (int s = 0; s < DS_; s++){ st[s] = decay*st[s] + dtx*sB[s]; y += st[s]*sC[s]; }
        yh[row*DI_ + tid] = y;
        __syncthreads();
    }
    #pragma unroll
    for (int s = 0; s < DS_; s++) st[s] = 0.f;
    // backward
    for (int v = V_-1; v >= 0; v--){
        long row = (long)b*V_ + v;
        if (tid < H_) sdt[tid] = dth[row*H_ + tid];
        else if (tid < H_+DS_) sB[tid-H_] = xbc[row*288 + 256 + (tid-H_)];
        else if (tid < H_+2*DS_) sC[tid-H_-DS_] = xbc[row*288 + 272 + (tid-H_-DS_)];
        __syncthreads();
        float dt = sdt[hh];
        float x = xbc[row*288 + tid];
        float decay = expf(dt*Ah);
        float dtx = dt*x;
        float y = 0.f;
        #pragma unroll
        for (int s = 0; s < DS_; s++){ st[s] = decay*st[s] + dtx*sB[s]; y += st[s]*sC[s]; }
        yh[row*DI_ + tid] += y + Dh*x;
        __syncthreads();
    }
}

// ---------------------------------------------------------------- gate with silu(zh) + RMSNorm
__global__ void gate_rms_kernel(float* __restrict__ yh, const float* __restrict__ zx,
                                const float* __restrict__ normw)
{
    int row = blockIdx.x; int c = threadIdx.x; // 256
    float g = yh[(long)row*DI_ + c] * siluf(zx[(long)row*552 + c]);
    __shared__ float red[256];
    red[c] = g*g;
    __syncthreads();
    for (int s = 128; s > 0; s >>= 1){
        if (c < s) red[c] += red[c+s];
        __syncthreads();
    }
    float scale = rsqrtf(red[0]/(float)DI_ + 1e-5f);
    yh[(long)row*DI_ + c] = g*scale*normw[c];
}

// ---------------------------------------------------------------- FiLM apply + transpose: fused[row, d*64+p] = gamma*tw[row,p,d]+beta
__global__ void film_kernel(const float* __restrict__ tw, const float* __restrict__ gb,
                            float* __restrict__ fused)
{
    int row = blockIdx.x; // 512
    for (int i = threadIdx.x; i < NF_; i += 256){
        int dd = i >> 6; int p = i & 63;
        float gamma = gb[(long)row*256 + dd];
        float beta  = gb[(long)row*256 + 128 + dd];
        fused[(long)row*NF_ + i] = gamma * tw[((long)row*P_ + p)*D_ + dd] + beta;
    }
}

// ---------------------------------------------------------------- head GEMM: out[row,j] = fused[row,:] . head_W[j,:] + b
__global__ void head_kernel(const float* __restrict__ fused, const float* __restrict__ W,
                            const float* __restrict__ bias, float* __restrict__ out)
{
    int row = blockIdx.x; // 512
    int tid = threadIdx.x; // 128
    __shared__ float s[2048];
    float acc = 0.f;
    for (int chunk = 0; chunk < NF_; chunk += 2048){
        for (int i = tid; i < 2048; i += 128) s[i] = fused[(long)row*NF_ + chunk + i];
        __syncthreads();
        if (tid < PRED_){
            const float* wp = W + (long)tid*NF_ + chunk;
            for (int k = 0; k < 2048; k += 4){
                float4 w4 = *(const float4*)(wp + k);
                acc += s[k]*w4.x + s[k+1]*w4.y + s[k+2]*w4.z + s[k+3]*w4.w;
            }
        }
        __syncthreads();
    }
    if (tid < PRED_) out[(long)row*PRED_ + tid] = acc + bias[tid];
}

// ---------------------------------------------------------------- final denorm + transpose to (B, PRED, V)
__global__ void final_kernel(const float* __restrict__ headout, const float* __restrict__ meanb,
                             const float* __restrict__ stdevb, float* __restrict__ outp)
{
    int idx = blockIdx.x*256 + threadIdx.x;
    if (idx >= B_*PRED_*V_) return;
    int b = idx / (PRED_*V_);
    int rem = idx % (PRED_*V_);
    int t = rem / V_; int v = rem % V_;
    int bv = b*V_ + v;
    outp[idx] = headout[(long)bv*PRED_ + t]*stdevb[bv] + meanb[bv];
}

extern "C" void kernel_launch(void* const* d_in, const int* in_sizes, int n_in,
                              void* d_out, int out_size, void* d_ws, size_t ws_size,
                              hipStream_t stream)
{
    const float* x_enc   = (const float*)d_in[0];
    const float* W_patch = (const float*)d_in[4];
    const float* b_patch = (const float*)d_in[5];
    const float* W_chan  = (const float*)d_in[6];
    const float* b_chan  = (const float*)d_in[7];
    const float* mb_Win  = (const float*)d_in[8];
    const float* mb_conv = (const float*)d_in[9];
    const float* mb_convb= (const float*)d_in[10];
    const float* mb_Wx   = (const float*)d_in[11];
    const float* mb_Wdt  = (const float*)d_in[12];
    const float* mb_bdt  = (const float*)d_in[13];
    const float* mb_Alog = (const float*)d_in[14];
    const float* mb_D    = (const float*)d_in[15];
    const float* mb_Wout = (const float*)d_in[16];
    const float* tf_W1   = (const float*)d_in[17];
    const float* tf_b1   = (const float*)d_in[18];
    const float* tf_W2   = (const float*)d_in[19];
    const float* tf_b2   = (const float*)d_in[20];
    const float* hy_Win  = (const float*)d_in[21];
    const float* hy_conv = (const float*)d_in[22];
    const float* hy_convb= (const float*)d_in[23];
    const float* hy_bdt  = (const float*)d_in[24];
    const float* hy_Alog = (const float*)d_in[25];
    const float* hy_D    = (const float*)d_in[26];
    const float* hy_normw= (const float*)d_in[27];
    const float* hy_Wout = (const float*)d_in[28];
    const float* cf_W1   = (const float*)d_in[29];
    const float* cf_b1   = (const float*)d_in[30];
    const float* cf_W2   = (const float*)d_in[31];
    const float* cf_b2   = (const float*)d_in[32];
    const float* film_W  = (const float*)d_in[33];
    const float* film_b  = (const float*)d_in[34];
    const float* head_W  = (const float*)d_in[35];
    const float* head_b  = (const float*)d_in[36];

    float* ws = (float*)d_ws;
    float* meanb  = ws;
    float* stdevb = ws + 512;
    float* xc     = ws + 1024;
    float* cw     = xc + (long)BV_*L_;        // 512*512
    float* tw     = cw + (long)BV_*D_;        // 512*128
    float* xmz    = tw + (long)NP_*D_;        // 32768*128
    float* dtbc   = xmz + (long)NP_*2*DI_;    // 32768*512
    float* zx     = dtbc + (long)NP_*40;
    float* xbc    = zx + (long)BV_*552;
    float* dthb   = xbc + (long)BV_*288;
    float* yh     = dthb + (long)BV_*H_;
    float* cw_enc = yh + (long)BV_*DI_;
    float* cfh    = cw_enc + (long)BV_*D_;
    float* gb     = cfh + (long)BV_*DFF_;
    float* headout= gb + (long)BV_*2*D_;
    float* hidden = xmz;   // reuse after scan
    float* fused  = xmz;   // reuse after FFN2

    auto gemm = [&](const float* A, int lda, const float* W, const float* bias,
                    const float* residual, int ldr, float* C, int ldc,
                    int M, int N, int K, int act){
        dim3 g((M+BM-1)/BM, (N+BN-1)/BN);
        gemm_kernel<<<g, dim3(256), 0, stream>>>(A, lda, W, bias, residual, ldr, C, ldc, M, N, K, act);
    };

    // 1. normalize + transpose
    stats_kernel<<<dim3(BV_), dim3(256), 0, stream>>>(x_enc, meanb, stdevb, xc);
    // 2. patch embed + channel embed
    patch_kernel<<<dim3(BV_), dim3(256), 0, stream>>>(xc, W_patch, b_patch, tw);
    chan_kernel<<<dim3(BV_), dim3(128), 0, stream>>>(xc, W_chan, b_chan, cw);
    // 3. mamba in-projection (splits into xm | z as contiguous (NP,512))
    gemm(tw, D_, mb_Win, nullptr, nullptr, 0, xmz, 2*DI_, NP_, 2*DI_, D_, 0);
    // 4. depthwise conv + silu on xm (in place)
    mamba_conv_kernel<<<dim3(BV_), dim3(DI_), 0, stream>>>(xmz, mb_conv, mb_convb);
    // 5. x-projection -> dt8|B|C
    gemm(xmz, 2*DI_, mb_Wx, nullptr, nullptr, 0, dtbc, 40, NP_, 40, DI_, 0);
    // 6. selective scan (fused dt proj + softplus + D skip + silu(z) gate), writes into xm cols
    mamba_scan_kernel<<<dim3(BV_), dim3(DI_), 0, stream>>>(xmz, dtbc, mb_Wdt, mb_bdt, mb_Alog, mb_D);
    // 7. out-projection
    gemm(xmz, 2*DI_, mb_Wout, nullptr, nullptr, 0, tw, D_, NP_, D_, DI_, 0);
    // 8. time FFN
    gemm(tw, D_, tf_W1, tf_b1, nullptr, 0, hidden, DFF_, NP_, DFF_, D_, 1);
    gemm(hidden, DFF_, tf_W2, tf_b2, tw, D_, tw, D_, NP_, D_, DFF_, 0);
    // 9. hy in-projection
    gemm(cw, D_, hy_Win, nullptr, nullptr, 0, zx, 552, BV_, 552, D_, 0);
    // 10. hy conv + dth
    hy_conv_kernel<<<dim3(B_), dim3(320), 0, stream>>>(zx, xbc, hy_conv, hy_convb);
    dth_kernel<<<dim3((BV_*H_+255)/256), dim3(256), 0, stream>>>(zx, hy_bdt, dthb);
    // 11. bidirectional SSD
    ssd_kernel<<<dim3(B_), dim3(256), 0, stream>>>(xbc, dthb, yh, hy_Alog, hy_D);
    // 12. gate + rmsnorm
    gate_rms_kernel<<<dim3(BV_), dim3(DI_), 0, stream>>>(yh, zx, hy_normw);
    // 13. hy out-projection
    gemm(yh, DI_, hy_Wout, nullptr, nullptr, 0, cw_enc, D_, BV_, D_, DI_, 0);
    // 14. channel FFN
    gemm(cw_enc, D_, cf_W1, cf_b1, nullptr, 0, cfh, DFF_, BV_, DFF_, D_, 1);
    gemm(cfh, DFF_, cf_W2, cf_b2, cw_enc, D_, cw_enc, D_, BV_, D_, DFF_, 0);
    // 15. FiLM params
    gemm(cw_enc, D_, film_W, film_b, nullptr, 0, gb, 2*D_, BV_, 2*D_, D_, 0);
    // 16. FiLM apply + transpose
    film_kernel<<<dim3(BV_), dim3(256), 0, stream>>>(tw, gb, fused);
    // 17. head
    head_kernel<<<dim3(BV_), dim3(128), 0, stream>>>(fused, head_W, head_b, headout);
    // 18. denorm + transpose
    final_kernel<<<dim3((B_*PRED_*V_+255)/256), dim3(256), 0, stream>>>(headout, meanb, stdevb, (float*)d_out);
}

// Round 2
// 762.408 us; speedup vs baseline: 1.4305x; 1.4305x over previous
//
#include <hip/hip_runtime.h>
#include <math.h>

#define B_    16
#define L_    512
#define V_    32
#define D_    128
#define DFF_  256
#define PL_   16
#define ST_   8
#define PRED_ 96
#define DI_   256
#define DS_   16
#define DTR_  8
#define H_    8
#define HD_   32
#define KC_   4
#define P_    64
#define NF_   8192
#define BV_   (B_*V_)    // 512
#define NP_   (BV_*P_)   // 32768

__device__ __forceinline__ float siluf(float x){ return x / (1.f + expf(-x)); }
__device__ __forceinline__ float geluf(float x){
    const float c = 0.7978845608028654f;
    float t = tanhf(c*(x + 0.044715f*x*x*x));
    return 0.5f*x*(1.f+t);
}
__device__ __forceinline__ float softplusf(float x){ return (x > 20.f) ? x : log1pf(expf(x)); }

// ---------------------------------------------------------------- stats + normalize + transpose
__global__ void stats_kernel(const float* __restrict__ x_enc, float* __restrict__ meanb,
                             float* __restrict__ stdevb, float* __restrict__ xc)
{
    int bv = blockIdx.x; int b = bv >> 5; int v = bv & 31;
    int tid = threadIdx.x; // 256
    float x0 = x_enc[((long)b*L_ + tid)*V_ + v];
    float x1 = x_enc[((long)b*L_ + tid + 256)*V_ + v];
    __shared__ float rs[256], rq[256];
    rs[tid] = x0 + x1; rq[tid] = x0*x0 + x1*x1;
    __syncthreads();
    for (int s = 128; s > 0; s >>= 1){
        if (tid < s){ rs[tid] += rs[tid+s]; rq[tid] += rq[tid+s]; }
        __syncthreads();
    }
    __shared__ float smean, sinv;
    if (tid == 0){
        float m = rs[0] / (float)L_;
        float var = rq[0] / (float)L_ - m*m;
        float sd = sqrtf(var + 1e-5f);
        meanb[bv] = m; stdevb[bv] = sd;
        smean = m; sinv = 1.f/sd;
    }
    __syncthreads();
    xc[(long)bv*L_ + tid]       = (x0 - smean)*sinv;
    xc[(long)bv*L_ + tid + 256] = (x1 - smean)*sinv;
}

// ---------------------------------------------------------------- patch embedding
__global__ void patch_kernel(const float* __restrict__ xc, const float* __restrict__ Wp,
                             const float* __restrict__ bp, float* __restrict__ tw)
{
    int bv = blockIdx.x;
    __shared__ float sx[L_ + ST_];       // 520
    __shared__ float sw[D_ * PL_];       // 2048
    for (int i = threadIdx.x; i < L_ + ST_; i += 256) sx[i] = xc[(long)bv*L_ + (i < L_ ? i : L_-1)];
    for (int i = threadIdx.x; i < D_*PL_; i += 256) sw[i] = Wp[i];
    __syncthreads();
    for (int o = threadIdx.x; o < P_*D_; o += 256){
        int p = o >> 7; int dd = o & 127;
        float acc = bp[dd];
        #pragma unroll
        for (int k = 0; k < PL_; k++) acc += sx[p*ST_ + k] * sw[dd*PL_ + k];
        tw[((long)bv*P_ + p)*D_ + dd] = acc;
    }
}

// ---------------------------------------------------------------- channel embedding (cw = xc @ W_chan.T + b)
__global__ void chan_kernel(const float* __restrict__ xc, const float* __restrict__ Wc,
                            const float* __restrict__ bc, float* __restrict__ cw)
{
    int bv = blockIdx.x; int tid = threadIdx.x; // 128
    __shared__ float sx[L_];
    for (int i = tid; i < L_; i += 128) sx[i] = xc[(long)bv*L_ + i];
    __syncthreads();
    const float* wp = Wc + (long)tid*L_;
    float acc = bc[tid];
    for (int k = 0; k < L_; k += 4){
        float4 w4 = *(const float4*)(wp + k);
        acc += sx[k]*w4.x + sx[k+1]*w4.y + sx[k+2]*w4.z + sx[k+3]*w4.w;
    }
    cw[(long)bv*D_ + tid] = acc;
}

// ---------------------------------------------------------------- generic fp32 GEMM: C = act(A@W^T + bias) (+ residual)
// A: (M, lda), uses cols 0..K-1.  W: (N, K) row-major.  act: 0 none, 1 gelu.
// Requires: M % 128 == 0, K % 16 == 0.
#define BM 128
#define BN 64
#define BK 16
__global__ __launch_bounds__(256) void gemm_kernel(
                            const float* __restrict__ A, int lda,
                            const float* __restrict__ W,
                            const float* __restrict__ bias,
                            const float* __restrict__ residual, int ldr,
                            float* __restrict__ C, int ldc,
                            int M, int N, int K, int act)
{
    __shared__ float As[BK][BM+4];   // 16B-aligned row stride (132*4 = 528)
    __shared__ float Ws[BK][BN+4];   // 68*4 = 272
    int tid = threadIdx.x;
    int br = blockIdx.x * BM;
    int bc = blockIdx.y * BN;
    int tr = (tid >> 4) * 8;
    int tc = (tid & 15) * 4;
    float acc[8][4] = {};
    for (int k0 = 0; k0 < K; k0 += BK){
        // stage A tile: 128x16 = 512 float4
        #pragma unroll
        for (int n = 0; n < 2; n++){
            int f = n*256 + tid;
            int r = f >> 2, c4 = f & 3;
            float4 v = *(const float4*)(A + (long)(br + r)*lda + k0 + c4*4);
            As[c4*4+0][r] = v.x; As[c4*4+1][r] = v.y;
            As[c4*4+2][r] = v.z; As[c4*4+3][r] = v.w;
        }
        // stage W tile: 64x16 = 256 float4
        {
            int r = tid >> 2, c4 = tid & 3;
            int gr = bc + r;
            float4 v;
            if (gr < N) v = *(const float4*)(W + (long)gr*K + k0 + c4*4);
            else        v = make_float4(0.f, 0.f, 0.f, 0.f);
            Ws[c4*4+0][r] = v.x; Ws[c4*4+1][r] = v.y;
            Ws[c4*4+2][r] = v.z; Ws[c4*4+3][r] = v.w;
        }
        __syncthreads();
        #pragma unroll
        for (int k = 0; k < BK; k++){
            float a[8], w[4];
            #pragma unroll
            for (int i = 0; i < 8; i++) a[i] = As[k][tr+i];
            #pragma unroll
            for (int j = 0; j < 4; j++) w[j] = Ws[k][tc+j];
            #pragma unroll
            for (int i = 0; i < 8; i++)
                #pragma unroll
                for (int j = 0; j < 4; j++)
                    acc[i][j] += a[i]*w[j];
        }
        __syncthreads();
    }
    #pragma unroll
    for (int i = 0; i < 8; i++){
        int gr = br + tr + i;
        #pragma unroll
        for (int j = 0; j < 4; j++){
            int gc = bc + tc + j;
            if (gc >= N) continue;
            float v = acc[i][j];
            if (bias) v += bias[gc];
            if (act == 1) v = geluf(v);
            if (residual) v += residual[(long)gr*ldr + gc];
            C[(long)gr*ldc + gc] = v;
        }
    }
}

// ---------------------------------------------------------------- mamba depthwise causal conv + silu (in place on xm cols of xmz)
__global__ void mamba_conv_kernel(float* __restrict__ xmz, const float* __restrict__ w,
                                  const float* __restrict__ b)
{
    int n = blockIdx.x; int d = threadIdx.x; // 256
    float w0 = w[d*4+0], w1 = w[d*4+1], w2 = w[d*4+2], w3 = w[d*4+3];
    float bb = b[d];
    float x1 = 0.f, x2 = 0.f, x3 = 0.f;
    for (int t = 0; t < P_; t++){
        long idx = ((long)n*P_ + t)*(2*DI_) + d;
        float x0 = xmz[idx];
        float y = w3*x0 + w2*x1 + w1*x2 + w0*x3 + bb;
        xmz[idx] = siluf(y);
        x3 = x2; x2 = x1; x1 = x0;
    }
}

// ---------------------------------------------------------------- mamba selective scan (fused dt-proj + softplus + gating)
__global__ void mamba_scan_kernel(float* __restrict__ xmz, const float* __restrict__ dtbc,
                                  const float* __restrict__ Wdt, const float* __restrict__ bdt,
                                  const float* __restrict__ Alog, const float* __restrict__ Dvec)
{
    int n = blockIdx.x; int d = threadIdx.x; // 256
    float A[DS_];
    #pragma unroll
    for (int s = 0; s < DS_; s++) A[s] = -expf(Alog[d*DS_ + s]);
    float wdt[DTR_];
    #pragma unroll
    for (int j = 0; j < DTR_; j++) wdt[j] = Wdt[d*DTR_ + j];
    float bd = bdt[d];
    float Dd = Dvec[d];
    float h[DS_] = {};
    __shared__ float sRow[40]; // dt8 | B16 | C16
    for (int t = 0; t < P_; t++){
        long row = (long)n*P_ + t;
        if (d < 40) sRow[d] = dtbc[row*40 + d];
        __syncthreads();
        float dtr = bd;
        #pragma unroll
        for (int j = 0; j < DTR_; j++) dtr += sRow[j]*wdt[j];
        float dt = softplusf(dtr);
        float x = xmz[row*(2*DI_) + d];
        float dtx = dt*x;
        float y = 0.f;
        #pragma unroll
        for (int s = 0; s < DS_; s++){
            h[s] = expf(dt*A[s])*h[s] + dtx*sRow[DTR_ + s];
            y += h[s]*sRow[DTR_ + DS_ + s];
        }
        y += Dd*x;
        float z = xmz[row*(2*DI_) + DI_ + d];
        xmz[row*(2*DI_) + d] = y * siluf(z);
        __syncthreads();
    }
}

// ---------------------------------------------------------------- hy depthwise conv + silu (zx cols 256..543 -> xbc)
__global__ void hy_conv_kernel(const float* __restrict__ zx, float* __restrict__ xbc,
                               const float* __restrict__ w, const float* __restrict__ b)
{
    int bb = blockIdx.x; int c = threadIdx.x; // 320 threads
    if (c >= 288) return;
    float w0 = w[c*4+0], w1 = w[c*4+1], w2 = w[c*4+2], w3 = w[c*4+3];
    float bias = b[c];
    float x1 = 0.f, x2 = 0.f, x3 = 0.f;
    for (int v = 0; v < V_; v++){
        float x0 = zx[((long)(bb*V_+v))*552 + 256 + c];
        float y = w3*x0 + w2*x1 + w1*x2 + w0*x3 + bias;
        xbc[((long)(bb*V_+v))*288 + c] = siluf(y);
        x3 = x2; x2 = x1; x1 = x0;
    }
}

// ---------------------------------------------------------------- dth = softplus(zx[...,544:552] + hy_bdt)
__global__ void dth_kernel(const float* __restrict__ zx, const float* __restrict__ bdt,
                           float* __restrict__ dth)
{
    int idx = blockIdx.x*256 + threadIdx.x;
    if (idx >= BV_*H_) return;
    int row = idx >> 3; int hh = idx & 7;
    dth[idx] = softplusf(zx[(long)row*552 + 544 + hh] + bdt[hh]);
}

// ---------------------------------------------------------------- bidirectional SSD scan
__global__ void ssd_kernel(const float* __restrict__ xbc, const float* __restrict__ dth,
                           float* __restrict__ yh, const float* __restrict__ Alog,
                           const float* __restrict__ Dvec)
{
    int b = blockIdx.x; int tid = threadIdx.x; // 256
    int hh = tid >> 5;
    float Ah = -expf(Alog[hh]);
    float Dh = Dvec[hh];
    __shared__ float sdt[H_], sB[DS_], sC[DS_];
    float st[DS_] = {};
    // forward
    for (int v = 0; v < V_; v++){
        long row = (long)b*V_ + v;
        if (tid < H_) sdt[tid] = dth[row*H_ + tid];
        else if (tid < H_+DS_) sB[tid-H_] = xbc[row*288 + 256 + (tid-H_)];
        else if (tid < H_+2*DS_) sC[tid-H_-DS_] = xbc[row*288 + 272 + (tid-H_-DS_)];
        __syncthreads();
        float dt = sdt[hh];
        float x = xbc[row*288 + tid];
        float decay = expf(dt*Ah);
        float dtx = dt*x;
        float y = 0.f;
        #pragma unroll
        for (int s = 0; s < DS_; s++){ st[s] = decay*st[s] + dtx*sB[s]; y += st[s]*sC[s]; }
        yh[row*DI_ + tid] = y;
        __syncthreads();
    }
    #pragma unroll
    for (int s = 0; s < DS_; s++) st[s] = 0.f;
    // backward
    for (int v = V_-1; v >= 0; v--){
        long row = (long)b*V_ + v;
        if (tid < H_) sdt[tid] = dth[row*H_ + tid];
        else if (tid < H_+DS_) sB[tid-H_] = xbc[row*288 + 256 + (tid-H_)];
        else if (tid < H_+2*DS_) sC[tid-H_-DS_] = xbc[row*288 + 272 + (tid-H_-DS_)];
        __syncthreads();
        float dt = sdt[hh];
        float x = xbc[row*288 + tid];
        float decay = expf(dt*Ah);
        float dtx = dt*x;
        float y = 0.f;
        #pragma unroll
        for (int s = 0; s < DS_; s++){ st[s] = decay*st[s] + dtx*sB[s]; y += st[s]*sC[s]; }
        yh[row*DI_ + tid] += y + Dh*x;
        __syncthreads();
    }
}

// ---------------------------------------------------------------- gate with silu(zh) + RMSNorm
__global__ void gate_rms_kernel(float* __restrict__ yh, const float* __restrict__ zx,
                                const float* __restrict__ normw)
{
    int row = blockIdx.x; int c = threadIdx.x; // 256
    float g = yh[(long)row*DI_ + c] * siluf(zx[(long)row*552 + c]);
    __shared__ float red[256];
    red[c] = g*g;
    __syncthreads();
    for (int s = 128; s > 0; s >>= 1){
        if (c < s) red[c] += red[c+s];
        __syncthreads();
    }
    float scale = rsqrtf(red[0]/(float)DI_ + 1e-5f);
    yh[(long)row*DI_ + c] = g*scale*normw[c];
}

// ---------------------------------------------------------------- FiLM apply + transpose (+ zero headout for split-K atomics)
__global__ void film_kernel(const float* __restrict__ tw, const float* __restrict__ gb,
                            float* __restrict__ fused, float* __restrict__ headout)
{
    int row = blockIdx.x; // 512
    if (threadIdx.x < PRED_) headout[(long)row*PRED_ + threadIdx.x] = 0.f;
    for (int i = threadIdx.x; i < NF_; i += 256){
        int dd = i >> 6; int p = i & 63;
        float gamma = gb[(long)row*256 + dd];
        float beta  = gb[(long)row*256 + 128 + dd];
        fused[(long)row*NF_ + i] = gamma * tw[((long)row*P_ + p)*D_ + dd] + beta;
    }
}

// ---------------------------------------------------------------- head split-K GEMM: out[r,j] += fused[r, kc-chunk] . W[j, kc-chunk]
// grid (16 row-tiles of 32, 32 K-chunks of 256), 256 threads.
__global__ __launch_bounds__(256) void head_split_kernel(
    const float* __restrict__ fused, const float* __restrict__ W,
    float* __restrict__ out)
{
    int rt = blockIdx.x;      // row tile (32 rows)
    int kc = blockIdx.y;      // K chunk (256)
    int tid = threadIdx.x;
    __shared__ float As[16][36];
    __shared__ float Ws[16][100];
    int tr = (tid >> 4) * 2;
    int tc = (tid & 15) * 6;
    float acc[2][6] = {};
    long kbase = (long)kc * 256;
    for (int kt = 0; kt < 256; kt += 16){
        if (tid < 128){
            int r = tid >> 2, c4 = tid & 3;
            float4 v = *(const float4*)(fused + (long)(rt*32 + r)*NF_ + kbase + kt + c4*4);
            As[c4*4+0][r] = v.x; As[c4*4+1][r] = v.y;
            As[c4*4+2][r] = v.z; As[c4*4+3][r] = v.w;
        }
        for (int f = tid; f < 384; f += 256){
            int j = f >> 2, c4 = f & 3;
            float4 v = *(const float4*)(W + (long)j*NF_ + kbase + kt + c4*4);
            Ws[c4*4+0][j] = v.x; Ws[c4*4+1][j] = v.y;
            Ws[c4*4+2][j] = v.z; Ws[c4*4+3][j] = v.w;
        }
        __syncthreads();
        #pragma unroll
        for (int k = 0; k < 16; k++){
            float a0 = As[k][tr], a1 = As[k][tr+1];
            float w[6];
            #pragma unroll
            for (int j = 0; j < 6; j++) w[j] = Ws[k][tc+j];
            #pragma unroll
            for (int j = 0; j < 6; j++){
                acc[0][j] += a0*w[j];
                acc[1][j] += a1*w[j];
            }
        }
        __syncthreads();
    }
    #pragma unroll
    for (int i = 0; i < 2; i++)
        #pragma unroll
        for (int j = 0; j < 6; j++)
            atomicAdd(&out[(long)(rt*32 + tr + i)*PRED_ + tc + j], acc[i][j]);
}

// ---------------------------------------------------------------- final denorm + bias + transpose to (B, PRED, V)
__global__ void final_kernel(const float* __restrict__ headout, const float* __restrict__ bias,
                             const float* __restrict__ meanb,
                             const float* __restrict__ stdevb, float* __restrict__ outp)
{
    int idx = blockIdx.x*256 + threadIdx.x;
    if (idx >= B_*PRED_*V_) return;
    int b = idx / (PRED_*V_);
    int rem = idx % (PRED_*V_);
    int t = rem / V_; int v = rem % V_;
    int bv = b*V_ + v;
    outp[idx] = (headout[(long)bv*PRED_ + t] + bias[t])*stdevb[bv] + meanb[bv];
}

extern "C" void kernel_launch(void* const* d_in, const int* in_sizes, int n_in,
                              void* d_out, int out_size, void* d_ws, size_t ws_size,
                              hipStream_t stream)
{
    const float* x_enc   = (const float*)d_in[0];
    const float* W_patch = (const float*)d_in[4];
    const float* b_patch = (const float*)d_in[5];
    const float* W_chan  = (const float*)d_in[6];
    const float* b_chan  = (const float*)d_in[7];
    const float* mb_Win  = (const float*)d_in[8];
    const float* mb_conv = (const float*)d_in[9];
    const float* mb_convb= (const float*)d_in[10];
    const float* mb_Wx   = (const float*)d_in[11];
    const float* mb_Wdt  = (const float*)d_in[12];
    const float* mb_bdt  = (const float*)d_in[13];
    const float* mb_Alog = (const float*)d_in[14];
    const float* mb_D    = (const float*)d_in[15];
    const float* mb_Wout = (const float*)d_in[16];
    const float* tf_W1   = (const float*)d_in[17];
    const float* tf_b1   = (const float*)d_in[18];
    const float* tf_W2   = (const float*)d_in[19];
    const float* tf_b2   = (const float*)d_in[20];
    const float* hy_Win  = (const float*)d_in[21];
    const float* hy_conv = (const float*)d_in[22];
    const float* hy_convb= (const float*)d_in[23];
    const float* hy_bdt  = (const float*)d_in[24];
    const float* hy_Alog = (const float*)d_in[25];
    const float* hy_D    = (const float*)d_in[26];
    const float* hy_normw= (const float*)d_in[27];
    const float* hy_Wout = (const float*)d_in[28];
    const float* cf_W1   = (const float*)d_in[29];
    const float* cf_b1   = (const float*)d_in[30];
    const float* cf_W2   = (const float*)d_in[31];
    const float* cf_b2   = (const float*)d_in[32];
    const float* film_W  = (const float*)d_in[33];
    const float* film_b  = (const float*)d_in[34];
    const float* head_W  = (const float*)d_in[35];
    const float* head_b  = (const float*)d_in[36];

    float* ws = (float*)d_ws;
    float* meanb  = ws;
    float* stdevb = ws + 512;
    float* xc     = ws + 1024;
    float* cw     = xc + (long)BV_*L_;        // 512*512
    float* tw     = cw + (long)BV_*D_;        // 512*128
    float* xmz    = tw + (long)NP_*D_;        // 32768*128
    float* dtbc   = xmz + (long)NP_*2*DI_;    // 32768*512
    float* zx     = dtbc + (long)NP_*40;
    float* xbc    = zx + (long)BV_*552;
    float* dthb   = xbc + (long)BV_*288;
    float* yh     = dthb + (long)BV_*H_;
    float* cw_enc = yh + (long)BV_*DI_;
    float* cfh    = cw_enc + (long)BV_*D_;
    float* gb     = cfh + (long)BV_*DFF_;
    float* headout= gb + (long)BV_*2*D_;
    float* hidden = xmz;   // reuse after scan
    float* fused  = xmz;   // reuse after FFN2

    auto gemm = [&](const float* A, int lda, const float* W, const float* bias,
                    const float* residual, int ldr, float* C, int ldc,
                    int M, int N, int K, int act){
        dim3 g((M+BM-1)/BM, (N+BN-1)/BN);
        gemm_kernel<<<g, dim3(256), 0, stream>>>(A, lda, W, bias, residual, ldr, C, ldc, M, N, K, act);
    };

    // 1. normalize + transpose
    stats_kernel<<<dim3(BV_), dim3(256), 0, stream>>>(x_enc, meanb, stdevb, xc);
    // 2. patch embed + channel embed
    patch_kernel<<<dim3(BV_), dim3(256), 0, stream>>>(xc, W_patch, b_patch, tw);
    chan_kernel<<<dim3(BV_), dim3(128), 0, stream>>>(xc, W_chan, b_chan, cw);
    // 3. mamba in-projection (splits into xm | z as contiguous (NP,512))
    gemm(tw, D_, mb_Win, nullptr, nullptr, 0, xmz, 2*DI_, NP_, 2*DI_, D_, 0);
    // 4. depthwise conv + silu on xm (in place)
    mamba_conv_kernel<<<dim3(BV_), dim3(DI_), 0, stream>>>(xmz, mb_conv, mb_convb);
    // 5. x-projection -> dt8|B|C
    gemm(xmz, 2*DI_, mb_Wx, nullptr, nullptr, 0, dtbc, 40, NP_, 40, DI_, 0);
    // 6. selective scan (fused dt proj + softplus + D skip + silu(z) gate), writes into xm cols
    mamba_scan_kernel<<<dim3(BV_), dim3(DI_), 0, stream>>>(xmz, dtbc, mb_Wdt, mb_bdt, mb_Alog, mb_D);
    // 7. out-projection
    gemm(xmz, 2*DI_, mb_Wout, nullptr, nullptr, 0, tw, D_, NP_, D_, DI_, 0);
    // 8. time FFN
    gemm(tw, D_, tf_W1, tf_b1, nullptr, 0, hidden, DFF_, NP_, DFF_, D_, 1);
    gemm(hidden, DFF_, tf_W2, tf_b2, tw, D_, tw, D_, NP_, D_, DFF_, 0);
    // 9. hy in-projection
    gemm(cw, D_, hy_Win, nullptr, nullptr, 0, zx, 552, BV_, 552, D_, 0);
    // 10. hy conv + dth
    hy_conv_kernel<<<dim3(B_), dim3(320), 0, stream>>>(zx, xbc, hy_conv, hy_convb);
    dth_kernel<<<dim3((BV_*H_+255)/256), dim3(256), 0, stream>>>(zx, hy_bdt, dthb);
    // 11. bidirectional SSD
    ssd_kernel<<<dim3(B_), dim3(256), 0, stream>>>(xbc, dthb, yh, hy_Alog, hy_D);
    // 12. gate + rmsnorm
    gate_rms_kernel<<<dim3(BV_), dim3(DI_), 0, stream>>>(yh, zx, hy_normw);
    // 13. hy out-projection
    gemm(yh, DI_, hy_Wout, nullptr, nullptr, 0, cw_enc, D_, BV_, D_, DI_, 0);
    // 14. channel FFN
    gemm(cw_enc, D_, cf_W1, cf_b1, nullptr, 0, cfh, DFF_, BV_, DFF_, D_, 1);
    gemm(cfh, DFF_, cf_W2, cf_b2, cw_enc, D_, cw_enc, D_, BV_, D_, DFF_, 0);
    // 15. FiLM params
    gemm(cw_enc, D_, film_W, film_b, nullptr, 0, gb, 2*D_, BV_, 2*D_, D_, 0);
    // 16. FiLM apply + transpose (+ zero headout)
    film_kernel<<<dim3(BV_), dim3(256), 0, stream>>>(tw, gb, fused, headout);
    // 17. head (split-K, atomic accumulate)
    head_split_kernel<<<dim3(16, 32), dim3(256), 0, stream>>>(fused, head_W, headout);
    // 18. denorm + bias + transpose
    final_kernel<<<dim3((B_*PRED_*V_+255)/256), dim3(256), 0, stream>>>(headout, head_b, meanb, stdevb, (float*)d_out);
}